// Round 8
// baseline (1393.557 us; speedup 1.0000x reference)
//
#include <hip/hip_runtime.h>
#include <hip/hip_bf16.h>

// v8: rolling-strip implicit-GEMM conv3x3(64->256) + bias + GELU + mean.
// bf16 MFMA 16x16x32, fp32 acc.
//
// Lesson from v5-v7: at 512 threads the (512,4) 128-reg cap is ~1 acc-vec
// short -> allocator spills acc (WRITE_SIZE 1-8 GB). Fix = change quantum:
// 256-thread blocks, launch_bounds(256,4) -> 4 blocks/CU (16 waves, 50%),
// wave workload = EXACTLY v3's proven-no-spill K-loop (64co x 64pix,
// acc[16]=64 AGPR, a[4]+b transient, ~45 arch VGPRs).
// Block = (n, half-row 64pix, group of 14 rows): rolling 4-slot LDS window
// (68 cols x 64 ci x 2B = 8704 B/slot, 34816 B total -> 4 blocks/CU),
// ONE barrier per row (slots r..r+2 read, r+3 written: disjoint mod 4).
// Staging per row: 64 cols x 64 ci (16 loads/thread) + 4 halo cols
// (1 clamped load/thread); all registers transient (die before the MFMAs --
// v4's cross-loop prefetch was the spill trigger, not the rolling idea).
// LDS layout: [slot][col][64ci] with PROVEN zero-conflict rotation swizzle
// blk_eff=(blk+col)&7 (v4/v6/v7 all measured 0 conflicts). B bases: 3 regs
// + hf*32 XOR; pf/slot offsets via small adds. Weights = fragment-linear wb2.
// Epilogue per row, fully transient: bias+GELU+mask+16-lane shuffle reduce+
// atomicAdd into prep-zeroed out. Halo garbage (right half cols 126/127)
// only corrupts masked B-columns; select `valid ? g : 0` contains it.

typedef __attribute__((ext_vector_type(8))) short short8;
typedef __attribute__((ext_vector_type(4))) float floatx4;
typedef __attribute__((ext_vector_type(4))) unsigned int uintx4;

#define ROWS 14
#define NGRP 9              // 9 * 14 = 126 output rows
#define SLOTC 4352          // 68 cols * 64 shorts per slot

__device__ __forceinline__ unsigned int f2bf(float f) {
    unsigned int u = __float_as_uint(f);
    return (u + 0x7FFFu + ((u >> 16) & 1u)) >> 16;   // RNE
}

__device__ __forceinline__ unsigned int pk2(float a, float b) {
    union { __hip_bfloat162 h; unsigned int u; } cv;
    cv.h = __float22bfloat162_rn(make_float2(a, b));  // x = low ci
    return cv.u;
}

__device__ __forceinline__ float gelu_t(float y) {
    float p = __builtin_fmaf(0.044715f, y * y, 1.0f);
    float e = exp2f(-2.3022084f * y * p);
    return y * __builtin_amdgcn_rcpf(1.0f + e);       // y*sigmoid(1.5957691*y*p)
}

__global__ __launch_bounds__(256)
void prep_kernel(const float* __restrict__ wgt, float* __restrict__ out,
                 unsigned short* __restrict__ wb2) {
    int g = blockIdx.x * 256 + threadIdx.x;
    if (g < 64 * 256) out[g] = 0.f;                   // zero the atomic target
    if (g < 147456) {                                 // 9 taps * 2 hf * 16 cog * 64 lane * 8
        int j    = g & 7;
        int lane = (g >> 3) & 63;
        int fc   = g >> 9;
        int cog  = fc & 15;
        int half = (fc >> 4) & 1;
        int tap  = fc >> 5;
        int li = lane & 15, quad = lane >> 4;
        int co = cog * 16 + li;
        int ci = half * 32 + quad * 8 + j;
        wb2[g] = (unsigned short)f2bf(wgt[(co * 64 + ci) * 9 + tap]);
    }
}

__global__ __launch_bounds__(256, 4)
void conv_kernel(const float* __restrict__ x, const float* __restrict__ bias,
                 const unsigned short* __restrict__ wb2, float* __restrict__ out) {
    __shared__ unsigned short xs[4 * SLOTC];          // 34816 B -> 4 blocks/CU

    const int bx  = blockIdx.x;
    const int n   = bx / (2 * NGRP);
    const int rem = bx % (2 * NGRP);
    const int c0  = (rem & 1) * 64;                   // half-row pixel base
    const int r0  = (rem >> 1) * ROWS;                // first output row

    const int tid  = threadIdx.x;
    const int lane = tid & 63;
    const int li   = lane & 15;
    const int quad = lane >> 4;
    const int sc   = __builtin_amdgcn_readfirstlane(tid >> 6);  // co quarter
    const int coBase = sc * 64;

    // ---- staging geometry (transient per row; nothing lives across MFMAs) ----
    const int colm = tid & 63;                        // main local col 0..63
    const int cig  = tid >> 6;                        // ci group of 16
    const float* xgm = x + (size_t)n * 64 * 16384
                     + (size_t)cig * 16 * 16384 + c0 + colm;
    const int wm0 = colm * 64 + ((2 * cig     + colm) & 7) * 8;  // rotation swizzle
    const int wm1 = colm * 64 + ((2 * cig + 1 + colm) & 7) * 8;
    const int cole = 64 + (tid & 3);                  // halo local cols 64..67
    const int cie  = tid >> 2;                        // 0..63
    const int xcol = (c0 + cole > 127) ? 127 : (c0 + cole);      // clamp (right half)
    const float* xge = x + (size_t)n * 64 * 16384 + (size_t)cie * 16384 + xcol;
    const int we = cole * 64 + (((cie >> 3) + cole) & 7) * 8 + (cie & 7);

#define STAGE(row, slot)                                                      \
    {                                                                         \
        float v[16];                                                          \
        _Pragma("unroll")                                                     \
        for (int k = 0; k < 16; ++k)                                          \
            v[k] = xgm[(size_t)k * 16384 + (row) * 128];                      \
        uintx4 p0, p1;                                                        \
        _Pragma("unroll")                                                     \
        for (int j = 0; j < 4; ++j) {                                         \
            p0[j] = pk2(v[2 * j],     v[2 * j + 1]);                          \
            p1[j] = pk2(v[8 + 2 * j], v[9 + 2 * j]);                          \
        }                                                                     \
        *reinterpret_cast<uintx4*>(&xs[(slot) * SLOTC + wm0]) = p0;           \
        *reinterpret_cast<uintx4*>(&xs[(slot) * SLOTC + wm1]) = p1;           \
        xs[(slot) * SLOTC + we] = (unsigned short)f2bf(xge[(row) * 128]);     \
    }

    // B-read bases (hf=0): local col = li+kw (+pf*16, swizzle-invariant mod 8)
    int bb3[3];
#pragma unroll
    for (int kw = 0; kw < 3; ++kw)
        bb3[kw] = (li + kw) * 64 + ((quad + li + kw) & 7) * 8;

    const unsigned short* abase = wb2 + (size_t)coBase * 32 + lane * 8;
    union Frag { uintx4 u; short8 s; };
    const float inv = 1.0f / (126.f * 126.f);

    // prologue: input rows r0, r0+1 -> slots 0, 1
    STAGE(r0, 0)
    STAGE(r0 + 1, 1)

#pragma unroll 1
    for (int r = 0; r < ROWS; ++r) {
        STAGE(r0 + r + 2, (r + 2) & 3)                // slot disjoint from reads
        __syncthreads();                              // one barrier per row

        floatx4 acc[16];                              // [cf][pf]
#pragma unroll
        for (int i = 0; i < 16; ++i) acc[i] = (floatx4){0.f, 0.f, 0.f, 0.f};

        const int sOff0 = (r & 3) * SLOTC;            // slot of input row r0+r
        const int sOff1 = ((r + 1) & 3) * SLOTC;
        const int sOff2 = ((r + 2) & 3) * SLOTC;

#pragma unroll
        for (int tap = 0; tap < 9; ++tap) {
            const int kh = tap / 3, kw = tap % 3;     // compile-time
            const int sOff = (kh == 0) ? sOff0 : (kh == 1) ? sOff1 : sOff2;
#pragma unroll
            for (int hf = 0; hf < 2; ++hf) {
                Frag a[4];
#pragma unroll
                for (int cf = 0; cf < 4; ++cf)
                    a[cf].u = *reinterpret_cast<const uintx4*>(
                        abase + (size_t)((tap * 2 + hf) * 16 + cf) * 512);
                const int bidx = (bb3[kw] ^ (hf * 32)) + sOff;
#pragma unroll
                for (int pf = 0; pf < 4; ++pf) {
                    Frag b;
                    b.u = *reinterpret_cast<const uintx4*>(&xs[bidx + pf * 1024]);
#pragma unroll
                    for (int cf = 0; cf < 4; ++cf)
                        acc[cf * 4 + pf] = __builtin_amdgcn_mfma_f32_16x16x32_bf16(
                            a[cf].s, b.s, acc[cf * 4 + pf], 0, 0, 0);
                }
            }
        }

        // ---- transient per-row epilogue ----
#pragma unroll
        for (int cf = 0; cf < 4; ++cf) {
            const floatx4 bv = *reinterpret_cast<const floatx4*>(
                bias + coBase + cf * 16 + quad * 4);
            floatx4 s = (floatx4){0.f, 0.f, 0.f, 0.f};
#pragma unroll
            for (int pf = 0; pf < 4; ++pf) {
                const bool valid = (c0 + pf * 16 + li) < 126;
#pragma unroll
                for (int r4 = 0; r4 < 4; ++r4) {
                    float g = gelu_t(acc[cf * 4 + pf][r4] + bv[r4]);
                    s[r4] += valid ? g : 0.f;         // contains halo garbage
                }
            }
#pragma unroll
            for (int r4 = 0; r4 < 4; ++r4) {
                float v = s[r4];
                v += __shfl_xor(v, 1);
                v += __shfl_xor(v, 2);
                v += __shfl_xor(v, 4);
                v += __shfl_xor(v, 8);
                if (li == 0)
                    atomicAdd(&out[n * 256 + coBase + cf * 16 + quad * 4 + r4],
                              v * inv);
            }
        }
        // no trailing barrier: next iter stages slot (r+3)&3, disjoint from
        // this iter's read set {r, r+1, r+2}&3 (all residues distinct mod 4)
    }
}

extern "C" void kernel_launch(void* const* d_in, const int* in_sizes, int n_in,
                              void* d_out, int out_size, void* d_ws, size_t ws_size,
                              hipStream_t stream) {
    const float* x    = (const float*)d_in[0];
    const float* wgt  = (const float*)d_in[1];
    const float* bias = (const float*)d_in[2];
    float* out = (float*)d_out;
    unsigned short* wb2 = (unsigned short*)d_ws;      // 294912 B, fragment-linear bf16

    prep_kernel<<<576, 256, 0, stream>>>(wgt, out, wb2);
    conv_kernel<<<64 * 2 * NGRP, 256, 0, stream>>>(x, bias, wb2, out);
}